// Round 16
// baseline (514.408 us; speedup 1.0000x reference)
//
#include <hip/hip_runtime.h>

typedef __attribute__((ext_vector_type(8))) short short8v;
typedef __attribute__((ext_vector_type(4))) float f32x4;

#define DT_TM 0.1f     // DT * TAU_MEM_INV
#define SYN_DEC 0.8f   // 1 - DT * TAU_SYN_INV
#define TT 16
#define BB 64
#define FCK 10816

// ---------------- ws layout, BIG path (bytes) ----------------
#define BO_S1   ((size_t)0)
#define BO_S2   ((size_t)29491200)
#define BO_S3   ((size_t)51642368)
#define BO_PART ((size_t)55836672)
#define BO_WH2  BO_PART
#define BO_WL2  (BO_PART + 102400)
#define BO_AFW  (BO_PART + 204800)
#define BO_WHF  ((size_t)72613888)
#define BO_WLF  ((size_t)94765056)
#define BIG_NEED ((size_t)116916224)

// ---------------- ws layout, FALLBACK path ----------------
#define FO_S1   ((size_t)0)
#define FO_S2   ((size_t)29491200)
#define FO_S3   ((size_t)40566784)
#define FO_PART ((size_t)44761088)
#define FO_V2   ((size_t)51576832)
#define FO_I2   ((size_t)51838976)
#define FO_WH2  FO_PART
#define FO_WL2  (FO_PART + 102400)

// ---------------------------------------------------------------------------
__device__ __forceinline__ unsigned short bf16_rne(float f) {
  unsigned int u = __float_as_uint(f);
  return (unsigned short)((u + 0x7FFFu + ((u >> 16) & 1u)) >> 16);
}

// K0a: split conv2 weights into bf16 hi/lo, layout [kk 25][oc 64][c 32]
__global__ __launch_bounds__(256) void k0_prep(
    const float* __restrict__ w2, unsigned short* __restrict__ whi,
    unsigned short* __restrict__ wlo) {
  int e = blockIdx.x * 256 + threadIdx.x;
  if (e >= 25 * 64 * 32) return;
  int kk = e >> 11;
  int rem = e & 2047;
  int oc = rem >> 5, c = rem & 31;
  float w = w2[(size_t)(oc * 32 + c) * 25 + kk];
  unsigned short hi = bf16_rne(w);
  float fhi = __uint_as_float((unsigned int)hi << 16);
  unsigned short lo = bf16_rne(w - fhi);
  whi[e] = hi;
  wlo[e] = lo;
}

// K0b: split wf into bf16 hi/lo, same [n][k] layout (elementwise)
__global__ __launch_bounds__(256) void k0b_wf(
    const float* __restrict__ wf, unsigned short* __restrict__ whiF,
    unsigned short* __restrict__ wloF) {
  size_t e = (size_t)blockIdx.x * 256 + threadIdx.x;
  if (e >= (size_t)1024 * FCK) return;
  float w = wf[e];
  unsigned short hi = bf16_rne(w);
  float fhi = __uint_as_float((unsigned int)hi << 16);
  whiF[e] = hi;
  wloF[e] = bf16_rne(w - fhi);
}

// K0w: conv1 A-fragment table, 3-way bf16 split, 5x6 tap layout.
__global__ __launch_bounds__(256) void k0w_prep(
    const float* __restrict__ w1, unsigned short* __restrict__ afw) {
  int e = blockIdx.x * 256 + threadIdx.x;
  if (e >= 9216) return;
  int i = e & 7, l = (e >> 3) & 63, f = e >> 9;
  int sp = f % 3, ks = (f / 3) % 3, mt = f / 9;
  int oc = mt * 16 + (l & 15);
  int tap = (l >> 4) * 8 + i;
  unsigned short out = 0;
  int ky = tap / 6, kx = tap - 6 * ky;
  if (tap < 30 && kx < 5) {
    float v = w1[(oc * 3 + ks) * 25 + ky * 5 + kx];
    unsigned short h = bf16_rne(v);
    if (sp == 0) out = h;
    else {
      float r1 = v - __uint_as_float((unsigned int)h << 16);
      unsigned short m = bf16_rne(r1);
      if (sp == 1) out = m;
      else out = bf16_rne(r1 - __uint_as_float((unsigned int)m << 16));
    }
  }
  afw[e] = out;
}

#define MFMA_BF16 __builtin_amdgcn_mfma_f32_16x16x32_bf16

// ---------------------------------------------------------------------------
// K1 (R16): conv1 MFMA with mt (oc-half) SPLIT ACROSS WAVES (R14 lesson):
// 512 thr = 8 waves = 2 mt x 4 pixel-groups. Per wave: 9 A-frags (36 VGPR,
// was 72), half the MFMAs, own LIF state + pool nibble. No per-t A-traffic
// (frags hoisted), so the R15 failure mode can't occur. Per-acc MFMA order
// unchanged -> bit-exact.
// ---------------------------------------------------------------------------
__global__ __launch_bounds__(512) void k1_mfma(
    const float* __restrict__ x, const unsigned short* __restrict__ afw,
    const float* __restrict__ b1, unsigned char* __restrict__ s1) {
  __shared__ unsigned int Hp[2][18 * 81];
  __shared__ unsigned int Mp[2][18 * 81];
  __shared__ unsigned int Lp[2][18 * 81];
  const int s = blockIdx.x;
  const int b = blockIdx.y;
  const int tid = threadIdx.x;
  const int wid = tid >> 6, l = tid & 63;
  const int mt = wid & 1, w = wid >> 1;     // mt 0..1, w 0..3
  const int n = l & 15, tg = l >> 4;
  const int xpix = 16 * w + n;
  const int xcl = (xpix < 60) ? xpix : 59;
  const bool storer = ((n & 1) == 0) && (xpix < 60);

  // hoist my mt's 9 A-frags (36 VGPR)
  short8v aw[3][3];
#pragma unroll
  for (int ks = 0; ks < 3; ++ks)
#pragma unroll
    for (int sp = 0; sp < 3; ++sp)
      aw[ks][sp] =
          *(const short8v*)(afw + (((mt * 3 + ks) * 3 + sp) * 64 + l) * 8);

  f32x4 bias = *(const f32x4*)&b1[mt * 16 + tg * 4];

  int poff[4];
#pragma unroll
  for (int i = 0; i < 4; ++i) {
    int tap = tg * 8 + 2 * i;
    int ky = tap / 6, kx = tap - 6 * ky;
    if (tap >= 30) { ky = 4; kx = 0; }
    poff[i] = ky * 81 + kx;
  }

  // staging jobs: 576 pair-pack jobs over 512 threads (+64 extra on wave 0)
  const int jrow0 = tid >> 5, jcp0 = tid & 31;
  const int jrow1 = (tid + 512) >> 5;
  const bool job1 = tid < 64;               // wave-uniform (wave 0 only)
  const int slan = (l & 32) | ((l + 1) & 31);

  float vst[2][4], ist[2][4];
#pragma unroll
  for (int a = 0; a < 2; ++a)
#pragma unroll
    for (int r = 0; r < 4; ++r) { vst[a][r] = 0.f; ist[a][r] = 0.f; }

  float2 pf0, pf1;

  auto phaseA = [&](int t) {
    const float* xp = x + ((size_t)(t * BB + b)) * 12288 + (size_t)(2 * s) * 64;
    {
      int c = jrow0 / 6, r = jrow0 - 6 * c;
      pf0 = *(const float2*)(xp + c * 4096 + r * 64 + 2 * jcp0);
    }
    if (job1) {
      int c = jrow1 / 6, r = jrow1 - 6 * c;
      pf1 = *(const float2*)(xp + c * 4096 + r * 64 + 2 * jcp0);
    }
  };

  auto phaseB = [&](int bfi) {
    unsigned int* H = Hp[bfi];
    unsigned int* M = Mp[bfi];
    unsigned int* L = Lp[bfi];
#pragma unroll
    for (int j = 0; j < 2; ++j) {
      if (j == 1 && !job1) break;
      float2 v2 = (j == 0) ? pf0 : pf1;
      int row = (j == 0) ? jrow0 : jrow1;
      int cp = jcp0;
      unsigned int h0 = bf16_rne(v2.x);
      float r0 = v2.x - __uint_as_float(h0 << 16);
      unsigned int m0 = bf16_rne(r0);
      unsigned int l0 = bf16_rne(r0 - __uint_as_float(m0 << 16));
      unsigned int h1 = bf16_rne(v2.y);
      float r1 = v2.y - __uint_as_float(h1 << 16);
      unsigned int m1 = bf16_rne(r1);
      unsigned int l1 = bf16_rne(r1 - __uint_as_float(m1 << 16));
      unsigned int hm0 = h0 | (m0 << 16);
      unsigned int hmN = (unsigned int)__shfl((int)hm0, slan);
      unsigned int lN  = (unsigned int)__shfl((int)l0, slan);
      int d = row * 81 + 2 * cp;
      H[d]     = h0 | (h1 << 16);
      H[d + 1] = h1 | (hmN << 16);
      M[d]     = m0 | (m1 << 16);
      M[d + 1] = m1 | (hmN & 0xffff0000u);
      L[d]     = l0 | (l1 << 16);
      L[d + 1] = l1 | (lN << 16);
    }
  };

  phaseA(0);
  phaseB(0);
  __syncthreads();

  for (int t = 0; t < TT; ++t) {
    const int cur = t & 1;
    if (t + 1 < TT) phaseA(t + 1);

    const unsigned int* H = Hp[cur];
    const unsigned int* M = Mp[cur];
    const unsigned int* L = Lp[cur];

    unsigned int pk[2];
#pragma unroll
    for (int nt = 0; nt < 2; ++nt) {
      f32x4 acc = (f32x4){0.f, 0.f, 0.f, 0.f};
#pragma unroll
      for (int ks = 0; ks < 3; ++ks) {
        const int base = (ks * 6 + nt) * 81 + xcl;
        union { unsigned int u[4]; short8v v; } fH, fM, fL;
#pragma unroll
        for (int i = 0; i < 4; ++i) {
          fH.u[i] = H[base + poff[i]];
          fM.u[i] = M[base + poff[i]];
          fL.u[i] = L[base + poff[i]];
        }
        // same per-acc order as champion: small -> large
        acc = MFMA_BF16(aw[ks][2], fH.v, acc, 0, 0, 0);
        acc = MFMA_BF16(aw[ks][1], fM.v, acc, 0, 0, 0);
        acc = MFMA_BF16(aw[ks][0], fL.v, acc, 0, 0, 0);
        acc = MFMA_BF16(aw[ks][1], fH.v, acc, 0, 0, 0);
        acc = MFMA_BF16(aw[ks][0], fM.v, acc, 0, 0, 0);
        acc = MFMA_BF16(aw[ks][0], fH.v, acc, 0, 0, 0);
      }
      unsigned int nib = 0;
#pragma unroll
      for (int r = 0; r < 4; ++r) {
        float inp = acc[r] + bias[r];
        float vd = vst[nt][r] + DT_TM * (ist[nt][r] - vst[nt][r]);
        float id = SYN_DEC * ist[nt][r];
        bool z = vd > 1.0f;
        vst[nt][r] = z ? 0.f : vd;
        ist[nt][r] = id + inp;
        nib |= (z ? 1u : 0u) << r;
      }
      pk[nt] = nib;
    }
    unsigned int pr = pk[0] | pk[1];
    unsigned int pc = pr | __shfl_xor(pr, 1);
    if (storer) {
      size_t base =
          (((size_t)(t * BB + b)) * 900 + (size_t)s * 30 + (xpix >> 1)) * 32 +
          mt * 16 + tg * 4;
      *(unsigned int*)&s1[base] =
          (pc & 1u) | ((pc & 2u) << 7) | ((pc & 4u) << 14) | ((pc & 8u) << 21);
    }
    if (t + 1 < TT) {
      phaseB((t + 1) & 1);
      __syncthreads();
    }
  }
}

// ---------------------------------------------------------------------------
// K1 fallback: fp32 scalar conv1
// ---------------------------------------------------------------------------
__global__ __launch_bounds__(256) void k1_conv1(
    const float* __restrict__ x, const float* __restrict__ w1,
    const float* __restrict__ b1, unsigned char* __restrict__ s1) {
  __shared__ float xs[3 * 64 * 68];
  const int oc = blockIdx.x;
  const int b  = blockIdx.y;
  const int tid = threadIdx.x;
  const bool valid = tid < 225;
  const int py0 = (tid / 15) * 2;
  const int px0 = (tid % 15) * 2;
  const int br = 2 * py0;
  const int bc = 2 * px0;

  float v[16], cur[16];
#pragma unroll
  for (int j = 0; j < 16; ++j) { v[j] = 0.f; cur[j] = 0.f; }
  const float bias = b1[oc];

  for (int t = 0; t < TT; ++t) {
    const float* xp = x + ((size_t)(t * BB + b)) * 12288;
#pragma unroll
    for (int k = 0; k < 12; ++k) {
      int e = tid + k * 256;
      int row = e >> 4, c4 = e & 15;
      ((float4*)xs)[row * 17 + c4] = ((const float4*)xp)[e];
    }
    __syncthreads();

    if (valid) {
      float acc[4][4];
#pragma unroll
      for (int r = 0; r < 4; ++r)
#pragma unroll
        for (int s = 0; s < 4; ++s) acc[r][s] = 0.f;

#pragma unroll
      for (int c = 0; c < 3; ++c) {
        const float* wp = w1 + (oc * 3 + c) * 25;
        float wv[25];
#pragma unroll
        for (int j = 0; j < 25; ++j) wv[j] = wp[j];
#pragma unroll
        for (int ri = 0; ri < 8; ++ri) {
          const float* rowp = &xs[(c * 64 + br + ri) * 68 + bc];
          float4 ra = *(const float4*)rowp;
          float4 rb = *(const float4*)(rowp + 4);
          float row[8] = {ra.x, ra.y, ra.z, ra.w, rb.x, rb.y, rb.z, rb.w};
#pragma unroll
          for (int r = 0; r < 4; ++r) {
            int ky = ri - r;
            if (ky >= 0 && ky < 5) {
#pragma unroll
              for (int kx = 0; kx < 5; ++kx) {
                float w = wv[ky * 5 + kx];
#pragma unroll
                for (int s = 0; s < 4; ++s) acc[r][s] += w * row[s + kx];
              }
            }
          }
        }
      }

      unsigned char pz00 = 0, pz01 = 0, pz10 = 0, pz11 = 0;
#pragma unroll
      for (int r = 0; r < 4; ++r)
#pragma unroll
        for (int s = 0; s < 4; ++s) {
          int j = r * 4 + s;
          float vd = v[j] + DT_TM * (cur[j] - v[j]);
          float id = SYN_DEC * cur[j];
          float inp = acc[r][s] + bias;
          bool z = vd > 1.0f;
          v[j] = z ? 0.f : vd;
          cur[j] = id + inp;
          if (z) {
            if (r < 2) { if (s < 2) pz00 = 1; else pz01 = 1; }
            else       { if (s < 2) pz10 = 1; else pz11 = 1; }
          }
        }
      size_t pixb = ((size_t)(t * BB + b)) * 900;
      s1[(pixb + (size_t)py0 * 30 + px0) * 32 + oc]           = pz00;
      s1[(pixb + (size_t)py0 * 30 + px0 + 1) * 32 + oc]       = pz01;
      s1[(pixb + (size_t)(py0 + 1) * 30 + px0) * 32 + oc]     = pz10;
      s1[(pixb + (size_t)(py0 + 1) * 30 + px0 + 1) * 32 + oc] = pz11;
    }
    __syncthreads();
  }
}

// ---------------------------------------------------------------------------
// K2 (R14 champion, verbatim): 512 thr = 8 waves = 2 og x 2 mi x 2 nc,
// NT=7/6/5, LIF state in LDS, T14 staging split. 195 us measured.
// ---------------------------------------------------------------------------
__device__ __forceinline__ void k2_stage_load(
    const unsigned char* __restrict__ s1, unsigned int (&pf)[6],
    int t, int b, int y0, int inRows) {
  const int tid = threadIdx.x;
  const unsigned char* sp =
      s1 + (((size_t)(t * BB + b)) * 900 + (size_t)y0 * 30) * 32;
  const int nelem = inRows * 240;
#pragma unroll
  for (int i = 0; i < 6; ++i) {
    int e = tid + i * 512;
    if (e < nelem) pf[i] = *(const unsigned int*)(sp + (size_t)e * 4);
  }
}

__device__ __forceinline__ void k2_stage_write(
    unsigned short* sl, const unsigned int (&pf)[6], int inRows) {
  const int tid = threadIdx.x;
  const int nelem = inRows * 240;
#pragma unroll
  for (int i = 0; i < 6; ++i) {
    int e = tid + i * 512;
    if (e < nelem) {
      unsigned int w = pf[i];
      unsigned int lo = ((w & 0xFFu) ? 0x3F80u : 0u) |
                        ((w & 0xFF00u) ? 0x3F800000u : 0u);
      unsigned int hi = ((w & 0xFF0000u) ? 0x3F80u : 0u) |
                        ((w & 0xFF000000u) ? 0x3F800000u : 0u);
      ((unsigned int*)sl)[e * 2]     = lo;
      ((unsigned int*)sl)[e * 2 + 1] = hi;
    }
  }
}

template<typename ST>
__device__ __forceinline__ void k2_pool(
    ST* __restrict__ s2, const unsigned char* zbuf, int t, int b, int y0, int R) {
  const int tid = threadIdx.x;
  const int prr = R >> 1;
  const int pcount = prr * 13 * 64;
  ST* s2p = s2 + ((size_t)(t * BB + b)) * 64 * 169;
  const int gpy0 = y0 >> 1;
  const ST one = (ST)((sizeof(ST) == 2) ? 0x3F80 : 1);
  for (int e = tid; e < pcount; e += 512) {
    int oc = e & 63, pp = e >> 6;
    int ppy = pp / 13, ppx = pp - ppy * 13;
    int base = (2 * ppy * 26 + 2 * ppx) * 68 + oc;
    unsigned char z = (unsigned char)(zbuf[base] | zbuf[base + 68] |
                      zbuf[base + 26 * 68] | zbuf[base + 26 * 68 + 68]);
    s2p[(size_t)oc * 169 + (gpy0 + ppy) * 13 + ppx] = z ? one : (ST)0;
  }
}

template<int NT>
__device__ __forceinline__ void k2_wave(
    const unsigned short* sl, float* Vst, float* Ist, unsigned char* zbuf,
    const unsigned short* __restrict__ whi, const unsigned short* __restrict__ wlo,
    const float* __restrict__ b2, int og, int mi, int q, int n,
    int ntstart, int npos) {
  int baddr[NT], pcl[NT];
  f32x4 acc[NT];
#pragma unroll
  for (int j = 0; j < NT; ++j) {
    int pl = (ntstart + j) * 16 + n;
    if (pl > npos - 1) pl = npos - 1;
    pcl[j] = pl;
    int ry = pl / 26, xx = pl - ry * 26;
    baddr[j] = (ry * 30 + xx) * 32 + q * 8;
    acc[j] = (f32x4){0.f, 0.f, 0.f, 0.f};
  }
  const int abase = (og * 32 + n) * 32 + q * 8 + mi * 512;
#pragma unroll 5
  for (int kk = 0; kk < 25; ++kk) {
    const int ky = kk / 5, kx = kk - (kk / 5) * 5;
    const int off = (ky * 30 + kx) * 32;
    short8v ah = *(const short8v*)(whi + kk * 2048 + abase);
    short8v al = *(const short8v*)(wlo + kk * 2048 + abase);
#pragma unroll
    for (int j = 0; j < NT; ++j) {
      short8v bv = *(const short8v*)(sl + baddr[j] + off);
      acc[j] = MFMA_BF16(al, bv, acc[j], 0, 0, 0);
      acc[j] = MFMA_BF16(ah, bv, acc[j], 0, 0, 0);
    }
  }
  const f32x4 bia = *(const f32x4*)&b2[og * 32 + mi * 16 + q * 4];
#pragma unroll
  for (int j = 0; j < NT; ++j) {
    int p = pcl[j];
    int sidx = p * 68 + og * 32 + mi * 16 + q * 4;
    f32x4 v4 = *(f32x4*)&Vst[sidx];
    f32x4 i4 = *(f32x4*)&Ist[sidx];
    f32x4 a = acc[j];
    unsigned char zr[4];
#pragma unroll
    for (int r = 0; r < 4; ++r) {
      float vd = v4[r] + DT_TM * (i4[r] - v4[r]);
      float id = SYN_DEC * i4[r];
      float inp = 10.f * (a[r] + bia[r]);
      bool z = vd > 1.0f;
      v4[r] = z ? 0.f : vd;
      i4[r] = id + inp;
      zr[r] = z ? 1 : 0;
    }
    *(f32x4*)&Vst[sidx] = v4;
    *(f32x4*)&Ist[sidx] = i4;
    *(uchar4*)&zbuf[sidx] = make_uchar4(zr[0], zr[1], zr[2], zr[3]);
  }
}

template<typename ST>
__global__ __launch_bounds__(512) void k2_mfma_l(
    const unsigned char* __restrict__ s1, const unsigned short* __restrict__ whi,
    const unsigned short* __restrict__ wlo, const float* __restrict__ b2,
    ST* __restrict__ s2) {
  __shared__ unsigned short sl[12 * 30 * 32];   // 23,040 B
  __shared__ float Vst[208 * 68];               // 56,576 B
  __shared__ float Ist[208 * 68];               // 56,576 B
  __shared__ unsigned char zbuf[208 * 68];      // 14,144 B (total 150,336)
  const int quad = blockIdx.x, b = blockIdx.y;
  const int tid = threadIdx.x;
  const int wid = tid >> 6, l = tid & 63;
  const int og = wid & 1, mi = (wid >> 1) & 1, nc = wid >> 2;   // nc 0..1
  const int q = l >> 4, n = l & 15;
  const int y0 = (quad == 0) ? 0 : (2 + quad * 6);
  const int R  = (quad == 0) ? 8 : 6;
  const int inRows = R + 4;
  const int npos = R * 26;

  for (int e = tid; e < 208 * 68; e += 512) { Vst[e] = 0.f; Ist[e] = 0.f; }

  unsigned int pf[6];
  k2_stage_load(s1, pf, 0, b, y0, inRows);
  k2_stage_write(sl, pf, inRows);
  __syncthreads();

  for (int t = 0; t < TT; ++t) {
    if (t + 1 < TT) k2_stage_load(s1, pf, t + 1, b, y0, inRows);

    if (quad == 0) {
      if (nc == 0)
        k2_wave<7>(sl, Vst, Ist, zbuf, whi, wlo, b2, og, mi, q, n, 0, npos);
      else
        k2_wave<6>(sl, Vst, Ist, zbuf, whi, wlo, b2, og, mi, q, n, 7, npos);
    } else {
      k2_wave<5>(sl, Vst, Ist, zbuf, whi, wlo, b2, og, mi, q, n, nc * 5, npos);
    }
    __syncthreads();

    k2_pool<ST>(s2, zbuf, t, b, y0, R);
    if (t + 1 < TT) k2_stage_write(sl, pf, inRows);
    __syncthreads();
  }
}

// ---------------------------------------------------------------------------
// K3g (BIG): one-shot FC GEMM, M=1024 (t*64+b), N=1024, K=10816, split-K 4.
// ---------------------------------------------------------------------------
__global__ __launch_bounds__(512) void k3g_fc(
    const unsigned short* __restrict__ s2,
    const unsigned short* __restrict__ whiF,
    const unsigned short* __restrict__ wloF,
    float* __restrict__ part) {
  __shared__ __align__(16) unsigned short As[128][72];
  __shared__ __align__(16) unsigned short Bh[128][72];
  __shared__ __align__(16) unsigned short Bl[128][72];
  const int tid = threadIdx.x;
  const int w = tid >> 6, l = tid & 63;
  const int mh = w & 1, nq = w >> 1;
  const int lr = l & 15, lk = l >> 4;
  const int n0 = blockIdx.x * 128, m0 = blockIdx.y * 128;
  const int ks = blockIdx.z;
  const int s_begin = (169 * ks) >> 2, s_end = (169 * (ks + 1)) >> 2;

  const int arow = tid >> 2, aseg = tid & 3;
  const unsigned short* ap = s2 + (size_t)(m0 + arow) * FCK + aseg * 16;
  unsigned short* aq = &As[0][0] + arow * 72 + aseg * 16;
  const int barr = tid >> 8, brem = tid & 255;
  const int bn = brem >> 1, bhalf = brem & 1;
  const unsigned short* bp =
      (barr ? wloF : whiF) + (size_t)(n0 + bn) * FCK + bhalf * 32;
  unsigned short* bq = (barr ? &Bl[0][0] : &Bh[0][0]) + bn * 72 + bhalf * 32;

  f32x4 acc[4][2];
#pragma unroll
  for (int mt = 0; mt < 4; ++mt)
#pragma unroll
    for (int nt = 0; nt < 2; ++nt) acc[mt][nt] = (f32x4){0.f, 0.f, 0.f, 0.f};

  for (int s = s_begin; s < s_end; ++s) {
    const size_t k0 = (size_t)s * 64;
    short8v a0 = *(const short8v*)(ap + k0);
    short8v a1 = *(const short8v*)(ap + k0 + 8);
    short8v b0 = *(const short8v*)(bp + k0);
    short8v b1 = *(const short8v*)(bp + k0 + 8);
    short8v b2v = *(const short8v*)(bp + k0 + 16);
    short8v b3 = *(const short8v*)(bp + k0 + 24);
    __syncthreads();
    *(short8v*)(aq)      = a0;
    *(short8v*)(aq + 8)  = a1;
    *(short8v*)(bq)      = b0;
    *(short8v*)(bq + 8)  = b1;
    *(short8v*)(bq + 16) = b2v;
    *(short8v*)(bq + 24) = b3;
    __syncthreads();
#pragma unroll
    for (int kt = 0; kt < 2; ++kt) {
      short8v bh0 = *(const short8v*)&Bh[nq * 32 + lr][kt * 32 + lk * 8];
      short8v bh1 = *(const short8v*)&Bh[nq * 32 + 16 + lr][kt * 32 + lk * 8];
      short8v bl0 = *(const short8v*)&Bl[nq * 32 + lr][kt * 32 + lk * 8];
      short8v bl1 = *(const short8v*)&Bl[nq * 32 + 16 + lr][kt * 32 + lk * 8];
#pragma unroll
      for (int mt = 0; mt < 4; ++mt) {
        short8v af = *(const short8v*)&As[mh * 64 + mt * 16 + lr][kt * 32 + lk * 8];
        acc[mt][0] = MFMA_BF16(af, bh0, acc[mt][0], 0, 0, 0);
        acc[mt][0] = MFMA_BF16(af, bl0, acc[mt][0], 0, 0, 0);
        acc[mt][1] = MFMA_BF16(af, bh1, acc[mt][1], 0, 0, 0);
        acc[mt][1] = MFMA_BF16(af, bl1, acc[mt][1], 0, 0, 0);
      }
    }
  }
  float* pp = part + ((size_t)ks << 20);
#pragma unroll
  for (int mt = 0; mt < 4; ++mt)
#pragma unroll
    for (int nt = 0; nt < 2; ++nt) {
      int mrow = m0 + mh * 64 + mt * 16 + lk * 4;
      int ncol = n0 + nq * 32 + nt * 16 + lr;
#pragma unroll
      for (int r = 0; r < 4; ++r)
        pp[(size_t)(mrow + r) * 1024 + ncol] = acc[mt][nt][r];
    }
}

// K3r (BIG): split-K reduce + bias + LIF2 recurrence over all t
__global__ __launch_bounds__(256) void k3r_lif2(
    const float* __restrict__ part, const float* __restrict__ bf,
    float* __restrict__ s3) {
  int e = blockIdx.x * 256 + threadIdx.x;
  int n = e & 1023;
  const float bias = bf[n];
  float v = 0.f, cur = 0.f;
  for (int t = 0; t < TT; ++t) {
    size_t idx = ((size_t)(t * BB) << 10) + e;
    float g = part[idx] + part[idx + (1u << 20)] +
              part[idx + (2u << 20)] + part[idx + (3u << 20)] + bias;
    float vd = v + DT_TM * (cur - v);
    float id = SYN_DEC * cur;
    bool sp = vd > 1.0f;
    v = sp ? 0.f : vd;
    cur = id + g;
    s3[(size_t)t * 65536 + e] = sp ? 1.f : 0.f;
  }
}

// ---------------------------------------------------------------------------
// Fallback K3a/K3b
// ---------------------------------------------------------------------------
__global__ __launch_bounds__(256) void k3a_fc(
    const unsigned char* __restrict__ s2, const float* __restrict__ wf,
    float* __restrict__ part, int t) {
  __shared__ float As[16][68];
  __shared__ float Bs[16][68];
  const int nt = blockIdx.x;
  const int ks = blockIdx.y;
  const int tid = threadIdx.x;
  const int N0 = nt * 64;
  const int kbase = ks * 416;
  const unsigned char* A = s2 + (size_t)t * BB * FCK;

  const int lm = tid >> 2;
  const int kq = tid & 3;
  const int m0 = (tid >> 4) << 2;
  const int n0 = (tid & 15) << 2;

  float acc[4][4];
#pragma unroll
  for (int i = 0; i < 4; ++i)
#pragma unroll
    for (int j = 0; j < 4; ++j) acc[i][j] = 0.f;

  for (int step = 0; step < 26; ++step) {
    int k0 = kbase + step * 16;
    uchar4 a4 = *(const uchar4*)&A[(size_t)lm * FCK + k0 + kq * 4];
    float4 b4 = *(const float4*)&wf[(size_t)(N0 + lm) * FCK + k0 + kq * 4];
    __syncthreads();
    As[kq * 4 + 0][lm] = (float)a4.x;
    As[kq * 4 + 1][lm] = (float)a4.y;
    As[kq * 4 + 2][lm] = (float)a4.z;
    As[kq * 4 + 3][lm] = (float)a4.w;
    Bs[kq * 4 + 0][lm] = b4.x;
    Bs[kq * 4 + 1][lm] = b4.y;
    Bs[kq * 4 + 2][lm] = b4.z;
    Bs[kq * 4 + 3][lm] = b4.w;
    __syncthreads();
#pragma unroll
    for (int kk = 0; kk < 16; ++kk) {
      float4 av = *(const float4*)&As[kk][m0];
      float4 bv = *(const float4*)&Bs[kk][n0];
      float a0 = av.x, a1 = av.y, a2 = av.z, a3 = av.w;
      acc[0][0] += a0 * bv.x; acc[0][1] += a0 * bv.y; acc[0][2] += a0 * bv.z; acc[0][3] += a0 * bv.w;
      acc[1][0] += a1 * bv.x; acc[1][1] += a1 * bv.y; acc[1][2] += a1 * bv.z; acc[1][3] += a1 * bv.w;
      acc[2][0] += a2 * bv.x; acc[2][1] += a2 * bv.y; acc[2][2] += a2 * bv.z; acc[2][3] += a2 * bv.w;
      acc[3][0] += a3 * bv.x; acc[3][1] += a3 * bv.y; acc[3][2] += a3 * bv.z; acc[3][3] += a3 * bv.w;
    }
  }
#pragma unroll
  for (int i = 0; i < 4; ++i)
#pragma unroll
    for (int j = 0; j < 4; ++j)
      part[((size_t)(ks * 64 + m0 + i)) * 1024 + N0 + n0 + j] = acc[i][j];
}

__global__ __launch_bounds__(256) void k3b_lif2(
    const float* __restrict__ part, const float* __restrict__ bf,
    float* __restrict__ v2, float* __restrict__ i2,
    float* __restrict__ s3, int t) {
  int e = blockIdx.x * 256 + threadIdx.x;
  int n = e & 1023;
  float s = 0.f;
#pragma unroll
  for (int ks = 0; ks < 26; ++ks) s += part[(size_t)ks * 65536 + e];
  float z = s + bf[n];
  float vv = v2[e], ii = i2[e];
  float vd = vv + DT_TM * (ii - vv);
  float id = SYN_DEC * ii;
  bool sp = vd > 1.0f;
  v2[e] = sp ? 0.f : vd;
  i2[e] = id + z;
  s3[(size_t)t * 65536 + e] = sp ? 1.f : 0.f;
}

// ---------------------------------------------------------------------------
// K4: readout, LI state in registers. out[t][b][10]
// ---------------------------------------------------------------------------
__global__ __launch_bounds__(320) void k4_out(
    const float* __restrict__ s3, const float* __restrict__ wo,
    const float* __restrict__ bo, float* __restrict__ out) {
  const int b = blockIdx.x;
  const int g = threadIdx.x >> 5;
  const int l = threadIdx.x & 31;
  float vv = 0.f, ii = 0.f;
  const float bg = bo[g];
  for (int t = 0; t < TT; ++t) {
    const float* zp = s3 + ((size_t)t * BB + b) * 1024;
    const float* wp = wo + g * 1024;
    float p = 0.f;
#pragma unroll 8
    for (int j = l; j < 1024; j += 32) p += zp[j] * wp[j];
#pragma unroll
    for (int off = 16; off; off >>= 1) p += __shfl_down(p, off, 32);
    float inp = p + bg;
    float vn = vv + DT_TM * (ii - vv);
    if (l == 0) out[(size_t)(t * BB + b) * 10 + g] = vn;
    ii = SYN_DEC * ii + inp;
    vv = vn;
  }
}

extern "C" void kernel_launch(void* const* d_in, const int* in_sizes, int n_in,
                              void* d_out, int out_size, void* d_ws, size_t ws_size,
                              hipStream_t stream) {
  (void)in_sizes; (void)n_in; (void)out_size;
  const float* x  = (const float*)d_in[0];
  const float* w1 = (const float*)d_in[1];
  const float* b1 = (const float*)d_in[2];
  const float* w2 = (const float*)d_in[3];
  const float* b2 = (const float*)d_in[4];
  const float* wf = (const float*)d_in[5];
  const float* bf = (const float*)d_in[6];
  const float* wo = (const float*)d_in[7];
  const float* bo = (const float*)d_in[8];
  float* out = (float*)d_out;
  char* ws = (char*)d_ws;

  if (ws_size >= BIG_NEED) {
    unsigned char*  s1   = (unsigned char*)(ws + BO_S1);
    unsigned short* s2   = (unsigned short*)(ws + BO_S2);
    float*          s3   = (float*)(ws + BO_S3);
    float*          part = (float*)(ws + BO_PART);
    unsigned short* wh2  = (unsigned short*)(ws + BO_WH2);
    unsigned short* wl2  = (unsigned short*)(ws + BO_WL2);
    unsigned short* afw  = (unsigned short*)(ws + BO_AFW);
    unsigned short* whiF = (unsigned short*)(ws + BO_WHF);
    unsigned short* wloF = (unsigned short*)(ws + BO_WLF);

    k0_prep<<<dim3(200), 256, 0, stream>>>(w2, wh2, wl2);
    k0w_prep<<<dim3(36), 256, 0, stream>>>(w1, afw);
    k0b_wf<<<dim3(43264), 256, 0, stream>>>(wf, whiF, wloF);
    k1_mfma<<<dim3(30, 64), 512, 0, stream>>>(x, afw, b1, s1);
    k2_mfma_l<unsigned short><<<dim3(4, 64), 512, 0, stream>>>(
        s1, wh2, wl2, b2, s2);
    k3g_fc<<<dim3(8, 8, 4), 512, 0, stream>>>(s2, whiF, wloF, part);
    k3r_lif2<<<dim3(256), 256, 0, stream>>>(part, bf, s3);
    k4_out<<<dim3(64), 320, 0, stream>>>(s3, wo, bo, out);
  } else {
    unsigned char*  s1   = (unsigned char*)(ws + FO_S1);
    unsigned char*  s2   = (unsigned char*)(ws + FO_S2);
    float*          s3   = (float*)(ws + FO_S3);
    float*          part = (float*)(ws + FO_PART);
    float*          v2   = (float*)(ws + FO_V2);
    float*          i2   = (float*)(ws + FO_I2);
    unsigned short* wh2  = (unsigned short*)(ws + FO_WH2);
    unsigned short* wl2  = (unsigned short*)(ws + FO_WL2);

    hipMemsetAsync(v2, 0, 2 * 65536 * sizeof(float), stream);
    k0_prep<<<dim3(200), 256, 0, stream>>>(w2, wh2, wl2);
    k1_conv1<<<dim3(32, 64), 256, 0, stream>>>(x, w1, b1, s1);
    k2_mfma_l<unsigned char><<<dim3(4, 64), 512, 0, stream>>>(s1, wh2, wl2, b2, s2);
    for (int t = 0; t < TT; ++t) {
      k3a_fc<<<dim3(16, 26), 256, 0, stream>>>(s2, wf, part, t);
      k3b_lif2<<<dim3(256), 256, 0, stream>>>(part, bf, v2, i2, s3, t);
    }
    k4_out<<<dim3(64), 320, 0, stream>>>(s3, wo, bo, out);
  }
}

// Round 17
// 444.108 us; speedup vs baseline: 1.1583x; 1.1583x over previous
//
#include <hip/hip_runtime.h>

typedef __attribute__((ext_vector_type(8))) short short8v;
typedef __attribute__((ext_vector_type(4))) float f32x4;

#define DT_TM 0.1f     // DT * TAU_MEM_INV
#define SYN_DEC 0.8f   // 1 - DT * TAU_SYN_INV
#define TT 16
#define BB 64
#define FCK 10816

// ---------------- ws layout, BIG path (bytes) ----------------
#define BO_S1   ((size_t)0)
#define BO_S2   ((size_t)29491200)
#define BO_S3   ((size_t)51642368)
#define BO_PART ((size_t)55836672)
#define BO_WH2  BO_PART
#define BO_WL2  (BO_PART + 102400)
#define BO_AFW  (BO_PART + 204800)
#define BO_WHF  ((size_t)72613888)
#define BO_WLF  ((size_t)94765056)
#define BIG_NEED ((size_t)116916224)

// ---------------- ws layout, FALLBACK path ----------------
#define FO_S1   ((size_t)0)
#define FO_S2   ((size_t)29491200)
#define FO_S3   ((size_t)40566784)
#define FO_PART ((size_t)44761088)
#define FO_V2   ((size_t)51576832)
#define FO_I2   ((size_t)51838976)
#define FO_WH2  FO_PART
#define FO_WL2  (FO_PART + 102400)

// ---------------------------------------------------------------------------
__device__ __forceinline__ unsigned short bf16_rne(float f) {
  unsigned int u = __float_as_uint(f);
  return (unsigned short)((u + 0x7FFFu + ((u >> 16) & 1u)) >> 16);
}

// K0a: split conv2 weights into bf16 hi/lo, layout [kk 25][oc 64][c 32]
__global__ __launch_bounds__(256) void k0_prep(
    const float* __restrict__ w2, unsigned short* __restrict__ whi,
    unsigned short* __restrict__ wlo) {
  int e = blockIdx.x * 256 + threadIdx.x;
  if (e >= 25 * 64 * 32) return;
  int kk = e >> 11;
  int rem = e & 2047;
  int oc = rem >> 5, c = rem & 31;
  float w = w2[(size_t)(oc * 32 + c) * 25 + kk];
  unsigned short hi = bf16_rne(w);
  float fhi = __uint_as_float((unsigned int)hi << 16);
  unsigned short lo = bf16_rne(w - fhi);
  whi[e] = hi;
  wlo[e] = lo;
}

// K0b: split wf into bf16 hi/lo, same [n][k] layout (elementwise)
__global__ __launch_bounds__(256) void k0b_wf(
    const float* __restrict__ wf, unsigned short* __restrict__ whiF,
    unsigned short* __restrict__ wloF) {
  size_t e = (size_t)blockIdx.x * 256 + threadIdx.x;
  if (e >= (size_t)1024 * FCK) return;
  float w = wf[e];
  unsigned short hi = bf16_rne(w);
  float fhi = __uint_as_float((unsigned int)hi << 16);
  whiF[e] = hi;
  wloF[e] = bf16_rne(w - fhi);
}

// K0w: conv1 A-fragment table, 3-way bf16 split, 5x6 tap layout.
__global__ __launch_bounds__(256) void k0w_prep(
    const float* __restrict__ w1, unsigned short* __restrict__ afw) {
  int e = blockIdx.x * 256 + threadIdx.x;
  if (e >= 9216) return;
  int i = e & 7, l = (e >> 3) & 63, f = e >> 9;
  int sp = f % 3, ks = (f / 3) % 3, mt = f / 9;
  int oc = mt * 16 + (l & 15);
  int tap = (l >> 4) * 8 + i;
  unsigned short out = 0;
  int ky = tap / 6, kx = tap - 6 * ky;
  if (tap < 30 && kx < 5) {
    float v = w1[(oc * 3 + ks) * 25 + ky * 5 + kx];
    unsigned short h = bf16_rne(v);
    if (sp == 0) out = h;
    else {
      float r1 = v - __uint_as_float((unsigned int)h << 16);
      unsigned short m = bf16_rne(r1);
      if (sp == 1) out = m;
      else out = bf16_rne(r1 - __uint_as_float((unsigned int)m << 16));
    }
  }
  afw[e] = out;
}

#define MFMA_BF16 __builtin_amdgcn_mfma_f32_16x16x32_bf16

// ---------------------------------------------------------------------------
// K1 (champion, R6 verbatim): conv1 via MFMA 6-term bf16 split + LIF + pool,
// 256 thr = 4 waves, both oc-halves per wave (aw[2][3][3], 72 VGPR hoisted),
// double-buffered pair-packed LDS planes, T14-style phaseA/phaseB split.
// ~130 us, ~3 blocks/CU. R16's mt-split (240 us) reverted: it doubled LDS
// B-reads (3.0e7 conflicts) for little occupancy gain.
// ---------------------------------------------------------------------------
__global__ __launch_bounds__(256) void k1_mfma(
    const float* __restrict__ x, const unsigned short* __restrict__ afw,
    const float* __restrict__ b1, unsigned char* __restrict__ s1) {
  __shared__ unsigned int Hp[2][18 * 81];
  __shared__ unsigned int Mp[2][18 * 81];
  __shared__ unsigned int Lp[2][18 * 81];
  const int s = blockIdx.x;
  const int b = blockIdx.y;
  const int tid = threadIdx.x;
  const int w = tid >> 6, l = tid & 63;
  const int n = l & 15, tg = l >> 4;
  const int xpix = 16 * w + n;
  const int xcl = (xpix < 60) ? xpix : 59;
  const bool storer = ((n & 1) == 0) && (xpix < 60);

  short8v aw[2][3][3];
#pragma unroll
  for (int mt = 0; mt < 2; ++mt)
#pragma unroll
    for (int ks = 0; ks < 3; ++ks)
#pragma unroll
      for (int sp = 0; sp < 3; ++sp)
        aw[mt][ks][sp] =
            *(const short8v*)(afw + (((mt * 3 + ks) * 3 + sp) * 64 + l) * 8);

  f32x4 bias0 = *(const f32x4*)&b1[tg * 4];
  f32x4 bias1 = *(const f32x4*)&b1[16 + tg * 4];

  int poff[4];
#pragma unroll
  for (int i = 0; i < 4; ++i) {
    int tap = tg * 8 + 2 * i;
    int ky = tap / 6, kx = tap - 6 * ky;
    if (tap >= 30) { ky = 4; kx = 0; }
    poff[i] = ky * 81 + kx;
  }

  const int jrow0 = tid >> 5, jcp0 = tid & 31;
  const int jrow1 = (tid + 256) >> 5;
  const int jrow2 = (tid + 512) >> 5;
  const bool job2 = tid < 64;
  const int slan = (l & 32) | ((l + 1) & 31);

  float vst[2][2][4], ist[2][2][4];
#pragma unroll
  for (int a = 0; a < 2; ++a)
#pragma unroll
    for (int m = 0; m < 2; ++m)
#pragma unroll
      for (int r = 0; r < 4; ++r) { vst[a][m][r] = 0.f; ist[a][m][r] = 0.f; }

  float2 pf0, pf1, pf2;

  auto phaseA = [&](int t) {
    const float* xp = x + ((size_t)(t * BB + b)) * 12288 + (size_t)(2 * s) * 64;
    {
      int c = jrow0 / 6, r = jrow0 - 6 * c;
      pf0 = *(const float2*)(xp + c * 4096 + r * 64 + 2 * jcp0);
    }
    {
      int c = jrow1 / 6, r = jrow1 - 6 * c;
      pf1 = *(const float2*)(xp + c * 4096 + r * 64 + 2 * jcp0);
    }
    if (job2) {
      int c = jrow2 / 6, r = jrow2 - 6 * c;
      pf2 = *(const float2*)(xp + c * 4096 + r * 64 + 2 * jcp0);
    }
  };

  auto phaseB = [&](int bfi) {
    unsigned int* H = Hp[bfi];
    unsigned int* M = Mp[bfi];
    unsigned int* L = Lp[bfi];
#pragma unroll
    for (int j = 0; j < 3; ++j) {
      if (j == 2 && !job2) break;
      float2 v2 = (j == 0) ? pf0 : (j == 1) ? pf1 : pf2;
      int row = (j == 0) ? jrow0 : (j == 1) ? jrow1 : jrow2;
      int cp = jcp0;
      unsigned int h0 = bf16_rne(v2.x);
      float r0 = v2.x - __uint_as_float(h0 << 16);
      unsigned int m0 = bf16_rne(r0);
      unsigned int l0 = bf16_rne(r0 - __uint_as_float(m0 << 16));
      unsigned int h1 = bf16_rne(v2.y);
      float r1 = v2.y - __uint_as_float(h1 << 16);
      unsigned int m1 = bf16_rne(r1);
      unsigned int l1 = bf16_rne(r1 - __uint_as_float(m1 << 16));
      unsigned int hm0 = h0 | (m0 << 16);
      unsigned int hmN = (unsigned int)__shfl((int)hm0, slan);
      unsigned int lN  = (unsigned int)__shfl((int)l0, slan);
      int d = row * 81 + 2 * cp;
      H[d]     = h0 | (h1 << 16);
      H[d + 1] = h1 | (hmN << 16);
      M[d]     = m0 | (m1 << 16);
      M[d + 1] = m1 | (hmN & 0xffff0000u);
      L[d]     = l0 | (l1 << 16);
      L[d + 1] = l1 | (lN << 16);
    }
  };

  phaseA(0);
  phaseB(0);
  __syncthreads();

  for (int t = 0; t < TT; ++t) {
    const int cur = t & 1;
    if (t + 1 < TT) phaseA(t + 1);

    const unsigned int* H = Hp[cur];
    const unsigned int* M = Mp[cur];
    const unsigned int* L = Lp[cur];

    unsigned int pk[2];
#pragma unroll
    for (int nt = 0; nt < 2; ++nt) {
      f32x4 acc0 = (f32x4){0.f, 0.f, 0.f, 0.f};
      f32x4 acc1 = (f32x4){0.f, 0.f, 0.f, 0.f};
#pragma unroll
      for (int ks = 0; ks < 3; ++ks) {
        const int base = (ks * 6 + nt) * 81 + xcl;
        union { unsigned int u[4]; short8v v; } fH, fM, fL;
#pragma unroll
        for (int i = 0; i < 4; ++i) {
          fH.u[i] = H[base + poff[i]];
          fM.u[i] = M[base + poff[i]];
          fL.u[i] = L[base + poff[i]];
        }
        acc0 = MFMA_BF16(aw[0][ks][2], fH.v, acc0, 0, 0, 0);
        acc1 = MFMA_BF16(aw[1][ks][2], fH.v, acc1, 0, 0, 0);
        acc0 = MFMA_BF16(aw[0][ks][1], fM.v, acc0, 0, 0, 0);
        acc1 = MFMA_BF16(aw[1][ks][1], fM.v, acc1, 0, 0, 0);
        acc0 = MFMA_BF16(aw[0][ks][0], fL.v, acc0, 0, 0, 0);
        acc1 = MFMA_BF16(aw[1][ks][0], fL.v, acc1, 0, 0, 0);
        acc0 = MFMA_BF16(aw[0][ks][1], fH.v, acc0, 0, 0, 0);
        acc1 = MFMA_BF16(aw[1][ks][1], fH.v, acc1, 0, 0, 0);
        acc0 = MFMA_BF16(aw[0][ks][0], fM.v, acc0, 0, 0, 0);
        acc1 = MFMA_BF16(aw[1][ks][0], fM.v, acc1, 0, 0, 0);
        acc0 = MFMA_BF16(aw[0][ks][0], fH.v, acc0, 0, 0, 0);
        acc1 = MFMA_BF16(aw[1][ks][0], fH.v, acc1, 0, 0, 0);
      }
      unsigned int nib0 = 0, nib1 = 0;
#pragma unroll
      for (int r = 0; r < 4; ++r) {
        float inp = acc0[r] + bias0[r];
        float vd = vst[nt][0][r] + DT_TM * (ist[nt][0][r] - vst[nt][0][r]);
        float id = SYN_DEC * ist[nt][0][r];
        bool z = vd > 1.0f;
        vst[nt][0][r] = z ? 0.f : vd;
        ist[nt][0][r] = id + inp;
        nib0 |= (z ? 1u : 0u) << r;

        float inp1 = acc1[r] + bias1[r];
        float vd1 = vst[nt][1][r] + DT_TM * (ist[nt][1][r] - vst[nt][1][r]);
        float id1 = SYN_DEC * ist[nt][1][r];
        bool z1 = vd1 > 1.0f;
        vst[nt][1][r] = z1 ? 0.f : vd1;
        ist[nt][1][r] = id1 + inp1;
        nib1 |= (z1 ? 1u : 0u) << r;
      }
      pk[nt] = nib0 | (nib1 << 4);
    }
    unsigned int pr = pk[0] | pk[1];
    unsigned int pc = pr | __shfl_xor(pr, 1);
    if (storer) {
      size_t base =
          (((size_t)(t * BB + b)) * 900 + (size_t)s * 30 + (xpix >> 1)) * 32 +
          tg * 4;
      unsigned int lo = pc & 0xFu, hi = (pc >> 4) & 0xFu;
      *(unsigned int*)&s1[base] =
          (lo & 1u) | ((lo & 2u) << 7) | ((lo & 4u) << 14) | ((lo & 8u) << 21);
      *(unsigned int*)&s1[base + 16] =
          (hi & 1u) | ((hi & 2u) << 7) | ((hi & 4u) << 14) | ((hi & 8u) << 21);
    }
    if (t + 1 < TT) {
      phaseB((t + 1) & 1);
      __syncthreads();
    }
  }
}

// ---------------------------------------------------------------------------
// K1 fallback: fp32 scalar conv1
// ---------------------------------------------------------------------------
__global__ __launch_bounds__(256) void k1_conv1(
    const float* __restrict__ x, const float* __restrict__ w1,
    const float* __restrict__ b1, unsigned char* __restrict__ s1) {
  __shared__ float xs[3 * 64 * 68];
  const int oc = blockIdx.x;
  const int b  = blockIdx.y;
  const int tid = threadIdx.x;
  const bool valid = tid < 225;
  const int py0 = (tid / 15) * 2;
  const int px0 = (tid % 15) * 2;
  const int br = 2 * py0;
  const int bc = 2 * px0;

  float v[16], cur[16];
#pragma unroll
  for (int j = 0; j < 16; ++j) { v[j] = 0.f; cur[j] = 0.f; }
  const float bias = b1[oc];

  for (int t = 0; t < TT; ++t) {
    const float* xp = x + ((size_t)(t * BB + b)) * 12288;
#pragma unroll
    for (int k = 0; k < 12; ++k) {
      int e = tid + k * 256;
      int row = e >> 4, c4 = e & 15;
      ((float4*)xs)[row * 17 + c4] = ((const float4*)xp)[e];
    }
    __syncthreads();

    if (valid) {
      float acc[4][4];
#pragma unroll
      for (int r = 0; r < 4; ++r)
#pragma unroll
        for (int s = 0; s < 4; ++s) acc[r][s] = 0.f;

#pragma unroll
      for (int c = 0; c < 3; ++c) {
        const float* wp = w1 + (oc * 3 + c) * 25;
        float wv[25];
#pragma unroll
        for (int j = 0; j < 25; ++j) wv[j] = wp[j];
#pragma unroll
        for (int ri = 0; ri < 8; ++ri) {
          const float* rowp = &xs[(c * 64 + br + ri) * 68 + bc];
          float4 ra = *(const float4*)rowp;
          float4 rb = *(const float4*)(rowp + 4);
          float row[8] = {ra.x, ra.y, ra.z, ra.w, rb.x, rb.y, rb.z, rb.w};
#pragma unroll
          for (int r = 0; r < 4; ++r) {
            int ky = ri - r;
            if (ky >= 0 && ky < 5) {
#pragma unroll
              for (int kx = 0; kx < 5; ++kx) {
                float w = wv[ky * 5 + kx];
#pragma unroll
                for (int s = 0; s < 4; ++s) acc[r][s] += w * row[s + kx];
              }
            }
          }
        }
      }

      unsigned char pz00 = 0, pz01 = 0, pz10 = 0, pz11 = 0;
#pragma unroll
      for (int r = 0; r < 4; ++r)
#pragma unroll
        for (int s = 0; s < 4; ++s) {
          int j = r * 4 + s;
          float vd = v[j] + DT_TM * (cur[j] - v[j]);
          float id = SYN_DEC * cur[j];
          float inp = acc[r][s] + bias;
          bool z = vd > 1.0f;
          v[j] = z ? 0.f : vd;
          cur[j] = id + inp;
          if (z) {
            if (r < 2) { if (s < 2) pz00 = 1; else pz01 = 1; }
            else       { if (s < 2) pz10 = 1; else pz11 = 1; }
          }
        }
      size_t pixb = ((size_t)(t * BB + b)) * 900;
      s1[(pixb + (size_t)py0 * 30 + px0) * 32 + oc]           = pz00;
      s1[(pixb + (size_t)py0 * 30 + px0 + 1) * 32 + oc]       = pz01;
      s1[(pixb + (size_t)(py0 + 1) * 30 + px0) * 32 + oc]     = pz10;
      s1[(pixb + (size_t)(py0 + 1) * 30 + px0 + 1) * 32 + oc] = pz11;
    }
    __syncthreads();
  }
}

// ---------------------------------------------------------------------------
// K2 (R14 champion, verbatim): 512 thr = 8 waves = 2 og x 2 mi x 2 nc,
// NT=7/6/5, LIF state in LDS, T14 staging split. 195 us measured.
// ---------------------------------------------------------------------------
__device__ __forceinline__ void k2_stage_load(
    const unsigned char* __restrict__ s1, unsigned int (&pf)[6],
    int t, int b, int y0, int inRows) {
  const int tid = threadIdx.x;
  const unsigned char* sp =
      s1 + (((size_t)(t * BB + b)) * 900 + (size_t)y0 * 30) * 32;
  const int nelem = inRows * 240;
#pragma unroll
  for (int i = 0; i < 6; ++i) {
    int e = tid + i * 512;
    if (e < nelem) pf[i] = *(const unsigned int*)(sp + (size_t)e * 4);
  }
}

__device__ __forceinline__ void k2_stage_write(
    unsigned short* sl, const unsigned int (&pf)[6], int inRows) {
  const int tid = threadIdx.x;
  const int nelem = inRows * 240;
#pragma unroll
  for (int i = 0; i < 6; ++i) {
    int e = tid + i * 512;
    if (e < nelem) {
      unsigned int w = pf[i];
      unsigned int lo = ((w & 0xFFu) ? 0x3F80u : 0u) |
                        ((w & 0xFF00u) ? 0x3F800000u : 0u);
      unsigned int hi = ((w & 0xFF0000u) ? 0x3F80u : 0u) |
                        ((w & 0xFF000000u) ? 0x3F800000u : 0u);
      ((unsigned int*)sl)[e * 2]     = lo;
      ((unsigned int*)sl)[e * 2 + 1] = hi;
    }
  }
}

template<typename ST>
__device__ __forceinline__ void k2_pool(
    ST* __restrict__ s2, const unsigned char* zbuf, int t, int b, int y0, int R) {
  const int tid = threadIdx.x;
  const int prr = R >> 1;
  const int pcount = prr * 13 * 64;
  ST* s2p = s2 + ((size_t)(t * BB + b)) * 64 * 169;
  const int gpy0 = y0 >> 1;
  const ST one = (ST)((sizeof(ST) == 2) ? 0x3F80 : 1);
  for (int e = tid; e < pcount; e += 512) {
    int oc = e & 63, pp = e >> 6;
    int ppy = pp / 13, ppx = pp - ppy * 13;
    int base = (2 * ppy * 26 + 2 * ppx) * 68 + oc;
    unsigned char z = (unsigned char)(zbuf[base] | zbuf[base + 68] |
                      zbuf[base + 26 * 68] | zbuf[base + 26 * 68 + 68]);
    s2p[(size_t)oc * 169 + (gpy0 + ppy) * 13 + ppx] = z ? one : (ST)0;
  }
}

template<int NT>
__device__ __forceinline__ void k2_wave(
    const unsigned short* sl, float* Vst, float* Ist, unsigned char* zbuf,
    const unsigned short* __restrict__ whi, const unsigned short* __restrict__ wlo,
    const float* __restrict__ b2, int og, int mi, int q, int n,
    int ntstart, int npos) {
  int baddr[NT], pcl[NT];
  f32x4 acc[NT];
#pragma unroll
  for (int j = 0; j < NT; ++j) {
    int pl = (ntstart + j) * 16 + n;
    if (pl > npos - 1) pl = npos - 1;
    pcl[j] = pl;
    int ry = pl / 26, xx = pl - ry * 26;
    baddr[j] = (ry * 30 + xx) * 32 + q * 8;
    acc[j] = (f32x4){0.f, 0.f, 0.f, 0.f};
  }
  const int abase = (og * 32 + n) * 32 + q * 8 + mi * 512;
#pragma unroll 5
  for (int kk = 0; kk < 25; ++kk) {
    const int ky = kk / 5, kx = kk - (kk / 5) * 5;
    const int off = (ky * 30 + kx) * 32;
    short8v ah = *(const short8v*)(whi + kk * 2048 + abase);
    short8v al = *(const short8v*)(wlo + kk * 2048 + abase);
#pragma unroll
    for (int j = 0; j < NT; ++j) {
      short8v bv = *(const short8v*)(sl + baddr[j] + off);
      acc[j] = MFMA_BF16(al, bv, acc[j], 0, 0, 0);
      acc[j] = MFMA_BF16(ah, bv, acc[j], 0, 0, 0);
    }
  }
  const f32x4 bia = *(const f32x4*)&b2[og * 32 + mi * 16 + q * 4];
#pragma unroll
  for (int j = 0; j < NT; ++j) {
    int p = pcl[j];
    int sidx = p * 68 + og * 32 + mi * 16 + q * 4;
    f32x4 v4 = *(f32x4*)&Vst[sidx];
    f32x4 i4 = *(f32x4*)&Ist[sidx];
    f32x4 a = acc[j];
    unsigned char zr[4];
#pragma unroll
    for (int r = 0; r < 4; ++r) {
      float vd = v4[r] + DT_TM * (i4[r] - v4[r]);
      float id = SYN_DEC * i4[r];
      float inp = 10.f * (a[r] + bia[r]);
      bool z = vd > 1.0f;
      v4[r] = z ? 0.f : vd;
      i4[r] = id + inp;
      zr[r] = z ? 1 : 0;
    }
    *(f32x4*)&Vst[sidx] = v4;
    *(f32x4*)&Ist[sidx] = i4;
    *(uchar4*)&zbuf[sidx] = make_uchar4(zr[0], zr[1], zr[2], zr[3]);
  }
}

template<typename ST>
__global__ __launch_bounds__(512) void k2_mfma_l(
    const unsigned char* __restrict__ s1, const unsigned short* __restrict__ whi,
    const unsigned short* __restrict__ wlo, const float* __restrict__ b2,
    ST* __restrict__ s2) {
  __shared__ unsigned short sl[12 * 30 * 32];   // 23,040 B
  __shared__ float Vst[208 * 68];               // 56,576 B
  __shared__ float Ist[208 * 68];               // 56,576 B
  __shared__ unsigned char zbuf[208 * 68];      // 14,144 B (total 150,336)
  const int quad = blockIdx.x, b = blockIdx.y;
  const int tid = threadIdx.x;
  const int wid = tid >> 6, l = tid & 63;
  const int og = wid & 1, mi = (wid >> 1) & 1, nc = wid >> 2;   // nc 0..1
  const int q = l >> 4, n = l & 15;
  const int y0 = (quad == 0) ? 0 : (2 + quad * 6);
  const int R  = (quad == 0) ? 8 : 6;
  const int inRows = R + 4;
  const int npos = R * 26;

  for (int e = tid; e < 208 * 68; e += 512) { Vst[e] = 0.f; Ist[e] = 0.f; }

  unsigned int pf[6];
  k2_stage_load(s1, pf, 0, b, y0, inRows);
  k2_stage_write(sl, pf, inRows);
  __syncthreads();

  for (int t = 0; t < TT; ++t) {
    if (t + 1 < TT) k2_stage_load(s1, pf, t + 1, b, y0, inRows);

    if (quad == 0) {
      if (nc == 0)
        k2_wave<7>(sl, Vst, Ist, zbuf, whi, wlo, b2, og, mi, q, n, 0, npos);
      else
        k2_wave<6>(sl, Vst, Ist, zbuf, whi, wlo, b2, og, mi, q, n, 7, npos);
    } else {
      k2_wave<5>(sl, Vst, Ist, zbuf, whi, wlo, b2, og, mi, q, n, nc * 5, npos);
    }
    __syncthreads();

    k2_pool<ST>(s2, zbuf, t, b, y0, R);
    if (t + 1 < TT) k2_stage_write(sl, pf, inRows);
    __syncthreads();
  }
}

// ---------------------------------------------------------------------------
// K3g (BIG): one-shot FC GEMM, M=1024 (t*64+b), N=1024, K=10816, split-K 4.
// ---------------------------------------------------------------------------
__global__ __launch_bounds__(512) void k3g_fc(
    const unsigned short* __restrict__ s2,
    const unsigned short* __restrict__ whiF,
    const unsigned short* __restrict__ wloF,
    float* __restrict__ part) {
  __shared__ __align__(16) unsigned short As[128][72];
  __shared__ __align__(16) unsigned short Bh[128][72];
  __shared__ __align__(16) unsigned short Bl[128][72];
  const int tid = threadIdx.x;
  const int w = tid >> 6, l = tid & 63;
  const int mh = w & 1, nq = w >> 1;
  const int lr = l & 15, lk = l >> 4;
  const int n0 = blockIdx.x * 128, m0 = blockIdx.y * 128;
  const int ks = blockIdx.z;
  const int s_begin = (169 * ks) >> 2, s_end = (169 * (ks + 1)) >> 2;

  const int arow = tid >> 2, aseg = tid & 3;
  const unsigned short* ap = s2 + (size_t)(m0 + arow) * FCK + aseg * 16;
  unsigned short* aq = &As[0][0] + arow * 72 + aseg * 16;
  const int barr = tid >> 8, brem = tid & 255;
  const int bn = brem >> 1, bhalf = brem & 1;
  const unsigned short* bp =
      (barr ? wloF : whiF) + (size_t)(n0 + bn) * FCK + bhalf * 32;
  unsigned short* bq = (barr ? &Bl[0][0] : &Bh[0][0]) + bn * 72 + bhalf * 32;

  f32x4 acc[4][2];
#pragma unroll
  for (int mt = 0; mt < 4; ++mt)
#pragma unroll
    for (int nt = 0; nt < 2; ++nt) acc[mt][nt] = (f32x4){0.f, 0.f, 0.f, 0.f};

  for (int s = s_begin; s < s_end; ++s) {
    const size_t k0 = (size_t)s * 64;
    short8v a0 = *(const short8v*)(ap + k0);
    short8v a1 = *(const short8v*)(ap + k0 + 8);
    short8v b0 = *(const short8v*)(bp + k0);
    short8v b1 = *(const short8v*)(bp + k0 + 8);
    short8v b2v = *(const short8v*)(bp + k0 + 16);
    short8v b3 = *(const short8v*)(bp + k0 + 24);
    __syncthreads();
    *(short8v*)(aq)      = a0;
    *(short8v*)(aq + 8)  = a1;
    *(short8v*)(bq)      = b0;
    *(short8v*)(bq + 8)  = b1;
    *(short8v*)(bq + 16) = b2v;
    *(short8v*)(bq + 24) = b3;
    __syncthreads();
#pragma unroll
    for (int kt = 0; kt < 2; ++kt) {
      short8v bh0 = *(const short8v*)&Bh[nq * 32 + lr][kt * 32 + lk * 8];
      short8v bh1 = *(const short8v*)&Bh[nq * 32 + 16 + lr][kt * 32 + lk * 8];
      short8v bl0 = *(const short8v*)&Bl[nq * 32 + lr][kt * 32 + lk * 8];
      short8v bl1 = *(const short8v*)&Bl[nq * 32 + 16 + lr][kt * 32 + lk * 8];
#pragma unroll
      for (int mt = 0; mt < 4; ++mt) {
        short8v af = *(const short8v*)&As[mh * 64 + mt * 16 + lr][kt * 32 + lk * 8];
        acc[mt][0] = MFMA_BF16(af, bh0, acc[mt][0], 0, 0, 0);
        acc[mt][0] = MFMA_BF16(af, bl0, acc[mt][0], 0, 0, 0);
        acc[mt][1] = MFMA_BF16(af, bh1, acc[mt][1], 0, 0, 0);
        acc[mt][1] = MFMA_BF16(af, bl1, acc[mt][1], 0, 0, 0);
      }
    }
  }
  float* pp = part + ((size_t)ks << 20);
#pragma unroll
  for (int mt = 0; mt < 4; ++mt)
#pragma unroll
    for (int nt = 0; nt < 2; ++nt) {
      int mrow = m0 + mh * 64 + mt * 16 + lk * 4;
      int ncol = n0 + nq * 32 + nt * 16 + lr;
#pragma unroll
      for (int r = 0; r < 4; ++r)
        pp[(size_t)(mrow + r) * 1024 + ncol] = acc[mt][nt][r];
    }
}

// K3r (BIG): split-K reduce + bias + LIF2 recurrence over all t
__global__ __launch_bounds__(256) void k3r_lif2(
    const float* __restrict__ part, const float* __restrict__ bf,
    float* __restrict__ s3) {
  int e = blockIdx.x * 256 + threadIdx.x;
  int n = e & 1023;
  const float bias = bf[n];
  float v = 0.f, cur = 0.f;
  for (int t = 0; t < TT; ++t) {
    size_t idx = ((size_t)(t * BB) << 10) + e;
    float g = part[idx] + part[idx + (1u << 20)] +
              part[idx + (2u << 20)] + part[idx + (3u << 20)] + bias;
    float vd = v + DT_TM * (cur - v);
    float id = SYN_DEC * cur;
    bool sp = vd > 1.0f;
    v = sp ? 0.f : vd;
    cur = id + g;
    s3[(size_t)t * 65536 + e] = sp ? 1.f : 0.f;
  }
}

// ---------------------------------------------------------------------------
// Fallback K3a/K3b
// ---------------------------------------------------------------------------
__global__ __launch_bounds__(256) void k3a_fc(
    const unsigned char* __restrict__ s2, const float* __restrict__ wf,
    float* __restrict__ part, int t) {
  __shared__ float As[16][68];
  __shared__ float Bs[16][68];
  const int nt = blockIdx.x;
  const int ks = blockIdx.y;
  const int tid = threadIdx.x;
  const int N0 = nt * 64;
  const int kbase = ks * 416;
  const unsigned char* A = s2 + (size_t)t * BB * FCK;

  const int lm = tid >> 2;
  const int kq = tid & 3;
  const int m0 = (tid >> 4) << 2;
  const int n0 = (tid & 15) << 2;

  float acc[4][4];
#pragma unroll
  for (int i = 0; i < 4; ++i)
#pragma unroll
    for (int j = 0; j < 4; ++j) acc[i][j] = 0.f;

  for (int step = 0; step < 26; ++step) {
    int k0 = kbase + step * 16;
    uchar4 a4 = *(const uchar4*)&A[(size_t)lm * FCK + k0 + kq * 4];
    float4 b4 = *(const float4*)&wf[(size_t)(N0 + lm) * FCK + k0 + kq * 4];
    __syncthreads();
    As[kq * 4 + 0][lm] = (float)a4.x;
    As[kq * 4 + 1][lm] = (float)a4.y;
    As[kq * 4 + 2][lm] = (float)a4.z;
    As[kq * 4 + 3][lm] = (float)a4.w;
    Bs[kq * 4 + 0][lm] = b4.x;
    Bs[kq * 4 + 1][lm] = b4.y;
    Bs[kq * 4 + 2][lm] = b4.z;
    Bs[kq * 4 + 3][lm] = b4.w;
    __syncthreads();
#pragma unroll
    for (int kk = 0; kk < 16; ++kk) {
      float4 av = *(const float4*)&As[kk][m0];
      float4 bv = *(const float4*)&Bs[kk][n0];
      float a0 = av.x, a1 = av.y, a2 = av.z, a3 = av.w;
      acc[0][0] += a0 * bv.x; acc[0][1] += a0 * bv.y; acc[0][2] += a0 * bv.z; acc[0][3] += a0 * bv.w;
      acc[1][0] += a1 * bv.x; acc[1][1] += a1 * bv.y; acc[1][2] += a1 * bv.z; acc[1][3] += a1 * bv.w;
      acc[2][0] += a2 * bv.x; acc[2][1] += a2 * bv.y; acc[2][2] += a2 * bv.z; acc[2][3] += a2 * bv.w;
      acc[3][0] += a3 * bv.x; acc[3][1] += a3 * bv.y; acc[3][2] += a3 * bv.z; acc[3][3] += a3 * bv.w;
    }
  }
#pragma unroll
  for (int i = 0; i < 4; ++i)
#pragma unroll
    for (int j = 0; j < 4; ++j)
      part[((size_t)(ks * 64 + m0 + i)) * 1024 + N0 + n0 + j] = acc[i][j];
}

__global__ __launch_bounds__(256) void k3b_lif2(
    const float* __restrict__ part, const float* __restrict__ bf,
    float* __restrict__ v2, float* __restrict__ i2,
    float* __restrict__ s3, int t) {
  int e = blockIdx.x * 256 + threadIdx.x;
  int n = e & 1023;
  float s = 0.f;
#pragma unroll
  for (int ks = 0; ks < 26; ++ks) s += part[(size_t)ks * 65536 + e];
  float z = s + bf[n];
  float vv = v2[e], ii = i2[e];
  float vd = vv + DT_TM * (ii - vv);
  float id = SYN_DEC * ii;
  bool sp = vd > 1.0f;
  v2[e] = sp ? 0.f : vd;
  i2[e] = id + z;
  s3[(size_t)t * 65536 + e] = sp ? 1.f : 0.f;
}

// ---------------------------------------------------------------------------
// K4: readout, LI state in registers. out[t][b][10]
// ---------------------------------------------------------------------------
__global__ __launch_bounds__(320) void k4_out(
    const float* __restrict__ s3, const float* __restrict__ wo,
    const float* __restrict__ bo, float* __restrict__ out) {
  const int b = blockIdx.x;
  const int g = threadIdx.x >> 5;
  const int l = threadIdx.x & 31;
  float vv = 0.f, ii = 0.f;
  const float bg = bo[g];
  for (int t = 0; t < TT; ++t) {
    const float* zp = s3 + ((size_t)t * BB + b) * 1024;
    const float* wp = wo + g * 1024;
    float p = 0.f;
#pragma unroll 8
    for (int j = l; j < 1024; j += 32) p += zp[j] * wp[j];
#pragma unroll
    for (int off = 16; off; off >>= 1) p += __shfl_down(p, off, 32);
    float inp = p + bg;
    float vn = vv + DT_TM * (ii - vv);
    if (l == 0) out[(size_t)(t * BB + b) * 10 + g] = vn;
    ii = SYN_DEC * ii + inp;
    vv = vn;
  }
}

extern "C" void kernel_launch(void* const* d_in, const int* in_sizes, int n_in,
                              void* d_out, int out_size, void* d_ws, size_t ws_size,
                              hipStream_t stream) {
  (void)in_sizes; (void)n_in; (void)out_size;
  const float* x  = (const float*)d_in[0];
  const float* w1 = (const float*)d_in[1];
  const float* b1 = (const float*)d_in[2];
  const float* w2 = (const float*)d_in[3];
  const float* b2 = (const float*)d_in[4];
  const float* wf = (const float*)d_in[5];
  const float* bf = (const float*)d_in[6];
  const float* wo = (const float*)d_in[7];
  const float* bo = (const float*)d_in[8];
  float* out = (float*)d_out;
  char* ws = (char*)d_ws;

  if (ws_size >= BIG_NEED) {
    unsigned char*  s1   = (unsigned char*)(ws + BO_S1);
    unsigned short* s2   = (unsigned short*)(ws + BO_S2);
    float*          s3   = (float*)(ws + BO_S3);
    float*          part = (float*)(ws + BO_PART);
    unsigned short* wh2  = (unsigned short*)(ws + BO_WH2);
    unsigned short* wl2  = (unsigned short*)(ws + BO_WL2);
    unsigned short* afw  = (unsigned short*)(ws + BO_AFW);
    unsigned short* whiF = (unsigned short*)(ws + BO_WHF);
    unsigned short* wloF = (unsigned short*)(ws + BO_WLF);

    k0_prep<<<dim3(200), 256, 0, stream>>>(w2, wh2, wl2);
    k0w_prep<<<dim3(36), 256, 0, stream>>>(w1, afw);
    k0b_wf<<<dim3(43264), 256, 0, stream>>>(wf, whiF, wloF);
    k1_mfma<<<dim3(30, 64), 256, 0, stream>>>(x, afw, b1, s1);
    k2_mfma_l<unsigned short><<<dim3(4, 64), 512, 0, stream>>>(
        s1, wh2, wl2, b2, s2);
    k3g_fc<<<dim3(8, 8, 4), 512, 0, stream>>>(s2, whiF, wloF, part);
    k3r_lif2<<<dim3(256), 256, 0, stream>>>(part, bf, s3);
    k4_out<<<dim3(64), 320, 0, stream>>>(s3, wo, bo, out);
  } else {
    unsigned char*  s1   = (unsigned char*)(ws + FO_S1);
    unsigned char*  s2   = (unsigned char*)(ws + FO_S2);
    float*          s3   = (float*)(ws + FO_S3);
    float*          part = (float*)(ws + FO_PART);
    float*          v2   = (float*)(ws + FO_V2);
    float*          i2   = (float*)(ws + FO_I2);
    unsigned short* wh2  = (unsigned short*)(ws + FO_WH2);
    unsigned short* wl2  = (unsigned short*)(ws + FO_WL2);

    hipMemsetAsync(v2, 0, 2 * 65536 * sizeof(float), stream);
    k0_prep<<<dim3(200), 256, 0, stream>>>(w2, wh2, wl2);
    k1_conv1<<<dim3(32, 64), 256, 0, stream>>>(x, w1, b1, s1);
    k2_mfma_l<unsigned char><<<dim3(4, 64), 512, 0, stream>>>(s1, wh2, wl2, b2, s2);
    for (int t = 0; t < TT; ++t) {
      k3a_fc<<<dim3(16, 26), 256, 0, stream>>>(s2, wf, part, t);
      k3b_lif2<<<dim3(256), 256, 0, stream>>>(part, bf, v2, i2, s3, t);
    }
    k4_out<<<dim3(64), 320, 0, stream>>>(s3, wo, bo, out);
  }
}